// Round 4
// baseline (46.587 us; speedup 1.0000x reference)
//
#include <hip/hip_runtime.h>
#include <hip/hip_bf16.h>

// HopfieldEnergy: energy_i = -(logsumexp_j(2 * xn_i . an_j) - log M)/2
//                 + 0.5*||xn_i||^2 + 0.5*max_j ||an_j||^2
// M = N = 8192, K = 256. Fused bf16-MFMA matmul + row exp-sum (no S matrix).
// 2*s in [-2,2] => sum exp() directly, no max subtraction.
// ||xn||^2 == ||an||^2 == 1 exactly => last two terms are the constant 1.0.

#define MROWS 8192
#define NROWS 8192
#define KDIM  256
#define BM    256
#define BN    32
#define NSPLIT 16

// 2*log2(e): xb holds (2*log2e)*x_n so exp(2*s) == exp2(acc) directly.
#define XSCALE 2.8853900817779268f

typedef __bf16 bf16x8 __attribute__((ext_vector_type(8)));
typedef float  f32x4  __attribute__((ext_vector_type(4)));

static __device__ __forceinline__ unsigned short f2bf(float f) {
    __hip_bfloat16 h = __float2bfloat16(f);
    union { __hip_bfloat16 h; unsigned short u; } c;
    c.h = h;
    return c.u;
}

// One wave per row. Rows [0,8192) = x, [8192,16384) = a.
// xb = (2*log2e)*x_n, linear. ab = a_n with each row's 16B chunks XOR-swizzled
// by ((j&7)<<4) so expsum can global_load_lds linearly and ds_read swizzled.
__global__ void normalize_kernel(const float* __restrict__ x,
                                 const float* __restrict__ a,
                                 __hip_bfloat16* __restrict__ xb,
                                 __hip_bfloat16* __restrict__ ab) {
    const int lane = threadIdx.x & 63;
    const int gwave = (blockIdx.x * blockDim.x + threadIdx.x) >> 6;
    const bool is_x = gwave < MROWS;
    const int r = is_x ? gwave : gwave - MROWS;
    const float* src = (is_x ? x : a) + (size_t)r * KDIM;

    float4 v = reinterpret_cast<const float4*>(src)[lane];
    float ss = v.x * v.x + v.y * v.y + v.z * v.z + v.w * v.w;
    #pragma unroll
    for (int o = 32; o > 0; o >>= 1) ss += __shfl_xor(ss, o);

    const float inv = 1.0f / fmaxf(sqrtf(ss), 1e-12f);
    const float scale = is_x ? (XSCALE * inv) : inv;

    union { ushort4 u4; unsigned short us[4]; } pk;
    pk.us[0] = f2bf(v.x * scale);
    pk.us[1] = f2bf(v.y * scale);
    pk.us[2] = f2bf(v.z * scale);
    pk.us[3] = f2bf(v.w * scale);

    if (is_x) {
        reinterpret_cast<ushort4*>(xb + (size_t)r * KDIM)[lane] = pk.u4;
    } else {
        char* base = (char*)(ab + (size_t)r * KDIM);
        const int off = (lane * 8) ^ ((r & 7) << 4);  // pre-swizzle source side
        *reinterpret_cast<ushort4*>(base + off) = pk.u4;
    }
}

// grid (MROWS/BM, NSPLIT), block 256 (4 waves). Wave owns 64 rows (f=4 A
// frags in 128 VGPRs), 32 cols. B tile double-buffered in LDS via
// global_load_lds (source pre-swizzled, LDS linear), swizzled ds_read_b128.
// T15-style: two acc sets; exp2 of step t-1 interleaved among step t's MFMAs
// so the trans/VALU tail hides under the matrix pipe instead of stalling at
// the barrier.  All acc indices compile-time (rule #20).
__global__ __launch_bounds__(256, 2) void expsum_kernel(
    const __hip_bfloat16* __restrict__ xb,
    const __hip_bfloat16* __restrict__ ab,
    float* __restrict__ partial) {
    __shared__ __attribute__((aligned(16))) char lds[2][BN * 512];

    const int tid = threadIdx.x;
    const int lane = tid & 63;
    const int w = tid >> 6;
    const int mbase = blockIdx.x * BM;
    const int jstart = blockIdx.y * (NROWS / NSPLIT);
    const int nsteps = (NROWS / NSPLIT) / BN;  // 16

    // A fragments: lane holds row (lane&15), k chunk (lane>>4)*8 (+ks*32).
    bf16x8 afrag[4][8];
    const int arow = mbase + w * 64 + (lane & 15);
    const int kb = (lane >> 4) * 8;
    #pragma unroll
    for (int f = 0; f < 4; ++f)
        #pragma unroll
        for (int ks = 0; ks < 8; ++ks)
            afrag[f][ks] = *reinterpret_cast<const bf16x8*>(
                xb + (size_t)(arow + f * 16) * KDIM + ks * 32 + kb);

    auto stage = [&](int buf, int j0) {
        const char* src = (const char*)ab + (size_t)j0 * 512;
        #pragma unroll
        for (int i = 0; i < 4; ++i) {
            const int chunk = w * 4 + i;  // 16 chunks x 1 KB = 16 KB tile
            __builtin_amdgcn_global_load_lds(
                (const __attribute__((address_space(1))) void*)
                    (src + chunk * 1024 + lane * 16),
                (__attribute__((address_space(3))) void*)
                    (&lds[buf][chunk * 1024]),
                16, 0, 0);
        }
    };

    float rowsum[4][4];
    #pragma unroll
    for (int f = 0; f < 4; ++f)
        #pragma unroll
        for (int r = 0; r < 4; ++r) rowsum[f][r] = 0.f;

    f32x4 accA[4][2], accB[4][2];

    // STEP body: barrier; prefetch t+1; MFMA step t into ACCW, interleaving
    // 4 exp2-accumulates of ACCE per ks (32 total) when DOEXP.
    // acc[f][g][r] = (2 log2e)*s[row=f*16+(lane>>4)*4+r][col=g*16+(lane&15)]
#define STEP(T, ACCW, ACCE, DOEXP)                                            \
    {                                                                         \
        const int t_ = (T);                                                   \
        __syncthreads();                                                      \
        if (t_ + 1 < nsteps) stage((t_ + 1) & 1, jstart + (t_ + 1) * BN);     \
        const char* L = lds[t_ & 1];                                          \
        _Pragma("unroll")                                                     \
        for (int f = 0; f < 4; ++f) {                                         \
            ACCW[f][0] = (f32x4){0.f, 0.f, 0.f, 0.f};                         \
            ACCW[f][1] = (f32x4){0.f, 0.f, 0.f, 0.f};                         \
        }                                                                     \
        _Pragma("unroll")                                                     \
        for (int ks = 0; ks < 8; ++ks) {                                      \
            const int bcol = ks * 64 + (lane >> 4) * 16;                      \
            const int r0 = lane & 15;                                         \
            const int sw = bcol ^ ((r0 & 7) << 4);                            \
            bf16x8 b0 = *reinterpret_cast<const bf16x8*>(&L[r0 * 512 + sw]); \
            bf16x8 b1 = *reinterpret_cast<const bf16x8*>(                     \
                &L[r0 * 512 + sw + 16 * 512]);                                \
            _Pragma("unroll")                                                 \
            for (int f = 0; f < 4; ++f) {                                     \
                ACCW[f][0] = __builtin_amdgcn_mfma_f32_16x16x32_bf16(         \
                    afrag[f][ks], b0, ACCW[f][0], 0, 0, 0);                   \
                ACCW[f][1] = __builtin_amdgcn_mfma_f32_16x16x32_bf16(         \
                    afrag[f][ks], b1, ACCW[f][1], 0, 0, 0);                   \
            }                                                                 \
            if (DOEXP) {                                                      \
                _Pragma("unroll")                                             \
                for (int u = 0; u < 4; ++u) {                                 \
                    const int e = ks * 4 + u;                                 \
                    rowsum[e >> 3][e & 3] += __builtin_amdgcn_exp2f(          \
                        ACCE[e >> 3][(e >> 2) & 1][e & 3]);                   \
                }                                                             \
            }                                                                 \
        }                                                                     \
    }

    stage(0, jstart);
    STEP(0, accA, accB, 0)                      // peeled: nothing to exp yet
    for (int tp = 1; tp <= nsteps - 3; tp += 2) {
        STEP(tp, accB, accA, 1)
        STEP(tp + 1, accA, accB, 1)
    }
    STEP(nsteps - 1, accB, accA, 1)             // step 15 -> accB
    #pragma unroll
    for (int e = 0; e < 32; ++e)                // drain last acc
        rowsum[e >> 3][e & 3] +=
            __builtin_amdgcn_exp2f(accB[e >> 3][(e >> 2) & 1][e & 3]);
#undef STEP

    // sum across the 16 lanes sharing (lane>>4)
    #pragma unroll
    for (int f = 0; f < 4; ++f)
        #pragma unroll
        for (int r = 0; r < 4; ++r) {
            float s = rowsum[f][r];
            s += __shfl_xor(s, 1);
            s += __shfl_xor(s, 2);
            s += __shfl_xor(s, 4);
            s += __shfl_xor(s, 8);
            rowsum[f][r] = s;
        }

    if ((lane & 15) == 0) {
        const int rbase = mbase + w * 64 + (lane >> 4) * 4;
        #pragma unroll
        for (int f = 0; f < 4; ++f)
            #pragma unroll
            for (int r = 0; r < 4; ++r)
                partial[(size_t)blockIdx.y * MROWS + rbase + f * 16 + r] = rowsum[f][r];
    }
}

__global__ void finalize_kernel(const float* __restrict__ partial,
                                float* __restrict__ out) {
    const int i = blockIdx.x * blockDim.x + threadIdx.x;
    float s = 0.f;
    #pragma unroll
    for (int p = 0; p < NSPLIT; ++p) s += partial[(size_t)p * MROWS + i];
    // sum holds Sum_j e^{2 s_ij}; energy = -(log(sum)-log M)/2 + 0.5 + 0.5
    out[i] = -0.5f * (logf(s) - logf((float)NROWS)) + 1.0f;
}

extern "C" void kernel_launch(void* const* d_in, const int* in_sizes, int n_in,
                              void* d_out, int out_size, void* d_ws, size_t ws_size,
                              hipStream_t stream) {
    const float* x = (const float*)d_in[0];
    const float* a = (const float*)d_in[1];
    float* out = (float*)d_out;

    char* ws = (char*)d_ws;
    size_t off = 0;
    __hip_bfloat16* xb = (__hip_bfloat16*)(ws + off); off += (size_t)MROWS * KDIM * 2;  // 4 MiB
    __hip_bfloat16* ab = (__hip_bfloat16*)(ws + off); off += (size_t)NROWS * KDIM * 2;  // 4 MiB
    float* partial     = (float*)(ws + off);          // NSPLIT*MROWS*4 = 512 KiB

    normalize_kernel<<<(2 * MROWS) / 4, 256, 0, stream>>>(x, a, xb, ab);
    expsum_kernel<<<dim3(MROWS / BM, NSPLIT), 256, 0, stream>>>(xb, ab, partial);
    finalize_kernel<<<MROWS / 256, 256, 0, stream>>>(partial, out);
}

// Round 5
// 46.287 us; speedup vs baseline: 1.0065x; 1.0065x over previous
//
#include <hip/hip_runtime.h>
#include <hip/hip_bf16.h>

// HopfieldEnergy: energy_i = -(logsumexp_j(2 * xn_i . an_j) - log M)/2
//                 + 0.5*||xn_i||^2 + 0.5*max_j ||an_j||^2
// M = N = 8192, K = 256. Fused bf16-MFMA matmul + row exp-sum (no S matrix).
// 2*s in [-2,2] => sum exp() directly, no max subtraction.
// ||xn||^2 == ||an||^2 == 1 exactly => last two terms are the constant 1.0.

#define MROWS 8192
#define NROWS 8192
#define KDIM  256
#define BM    256
#define BN    64
#define NSPLIT 16

// 2*log2(e): xb holds (2*log2e)*x_n so exp(2*s) == exp2(acc) directly.
#define XSCALE 2.8853900817779268f

typedef __bf16 bf16x8 __attribute__((ext_vector_type(8)));
typedef float  f32x4  __attribute__((ext_vector_type(4)));

static __device__ __forceinline__ unsigned short f2bf(float f) {
    __hip_bfloat16 h = __float2bfloat16(f);
    union { __hip_bfloat16 h; unsigned short u; } c;
    c.h = h;
    return c.u;
}

// One wave per row. Rows [0,8192) = x, [8192,16384) = a.
// xb = (2*log2e)*x_n, linear. ab = a_n with each row's 16B chunks XOR-swizzled
// by ((j&7)<<4) so expsum can global_load_lds linearly and ds_read swizzled.
__global__ void normalize_kernel(const float* __restrict__ x,
                                 const float* __restrict__ a,
                                 __hip_bfloat16* __restrict__ xb,
                                 __hip_bfloat16* __restrict__ ab) {
    const int lane = threadIdx.x & 63;
    const int gwave = (blockIdx.x * blockDim.x + threadIdx.x) >> 6;
    const bool is_x = gwave < MROWS;
    const int r = is_x ? gwave : gwave - MROWS;
    const float* src = (is_x ? x : a) + (size_t)r * KDIM;

    float4 v = reinterpret_cast<const float4*>(src)[lane];
    float ss = v.x * v.x + v.y * v.y + v.z * v.z + v.w * v.w;
    #pragma unroll
    for (int o = 32; o > 0; o >>= 1) ss += __shfl_xor(ss, o);

    const float inv = 1.0f / fmaxf(sqrtf(ss), 1e-12f);
    const float scale = is_x ? (XSCALE * inv) : inv;

    union { ushort4 u4; unsigned short us[4]; } pk;
    pk.us[0] = f2bf(v.x * scale);
    pk.us[1] = f2bf(v.y * scale);
    pk.us[2] = f2bf(v.z * scale);
    pk.us[3] = f2bf(v.w * scale);

    if (is_x) {
        reinterpret_cast<ushort4*>(xb + (size_t)r * KDIM)[lane] = pk.u4;
    } else {
        char* base = (char*)(ab + (size_t)r * KDIM);
        const int off = (lane * 8) ^ ((r & 7) << 4);  // pre-swizzle source side
        *reinterpret_cast<ushort4*>(base + off) = pk.u4;
    }
}

// grid (MROWS/BM, NSPLIT), block 256 (4 waves). Wave owns 64 rows (f=4 A
// frags in 128 VGPRs). B tile (BN=64 a-rows) double-buffered in LDS via
// global_load_lds (source pre-swizzled, LDS linear), swizzled ds_read_b128.
// Per step: two col-sub-steps of 32; explicit ks+1 B prefetch into named
// regs so ds_read latency hides under MFMA issue; setprio(1) on MFMA cluster.
__global__ __launch_bounds__(256, 2) void expsum_kernel(
    const __hip_bfloat16* __restrict__ xb,
    const __hip_bfloat16* __restrict__ ab,
    float* __restrict__ partial) {
    __shared__ __attribute__((aligned(16))) char lds[2][BN * 512];

    const int tid = threadIdx.x;
    const int lane = tid & 63;
    const int w = tid >> 6;
    const int mbase = blockIdx.x * BM;
    const int jstart = blockIdx.y * (NROWS / NSPLIT);
    const int nsteps = (NROWS / NSPLIT) / BN;  // 8

    // A fragments: lane holds row (lane&15), k chunk (lane>>4)*8 (+ks*32).
    bf16x8 afrag[4][8];
    const int arow = mbase + w * 64 + (lane & 15);
    const int kb = (lane >> 4) * 8;
    #pragma unroll
    for (int f = 0; f < 4; ++f)
        #pragma unroll
        for (int ks = 0; ks < 8; ++ks)
            afrag[f][ks] = *reinterpret_cast<const bf16x8*>(
                xb + (size_t)(arow + f * 16) * KDIM + ks * 32 + kb);

    auto stage = [&](int buf, int j0) {
        const char* src = (const char*)ab + (size_t)j0 * 512;
        #pragma unroll
        for (int i = 0; i < 8; ++i) {
            const int chunk = w * 8 + i;  // 32 chunks x 1 KB = 32 KB tile
            __builtin_amdgcn_global_load_lds(
                (const __attribute__((address_space(1))) void*)
                    (src + chunk * 1024 + lane * 16),
                (__attribute__((address_space(3))) void*)
                    (&lds[buf][chunk * 1024]),
                16, 0, 0);
        }
    };

    float rowsum[4][4];
    #pragma unroll
    for (int f = 0; f < 4; ++f)
        #pragma unroll
        for (int r = 0; r < 4; ++r) rowsum[f][r] = 0.f;

    const int cb = (lane >> 4) * 16;  // byte col base within a k-group
    const int rl = lane & 15;

    stage(0, jstart);

    for (int step = 0; step < nsteps; ++step) {
        __syncthreads();  // stage(step) drained (vmcnt0); prev buf reads done
        if (step + 1 < nsteps) stage((step + 1) & 1, jstart + (step + 1) * BN);
        const char* L = lds[step & 1];

        #pragma unroll
        for (int sub = 0; sub < 2; ++sub) {
            const int r0 = rl + sub * 32;
            const int r1 = r0 + 16;
            const char* p0 = &L[r0 * 512 + (((r0 & 7) << 4))];
            const char* p1 = &L[r1 * 512 + (((r1 & 7) << 4))];
            // address = row*512 + (bcol ^ ((row&7)<<4)); bcol bits don't
            // overlap the XOR bits only for bcol<64... they do at bit6, so
            // recompute the XOR per read (cheap, compile-time folded).
            f32x4 acc[4][2];
            #pragma unroll
            for (int f = 0; f < 4; ++f) {
                acc[f][0] = (f32x4){0.f, 0.f, 0.f, 0.f};
                acc[f][1] = (f32x4){0.f, 0.f, 0.f, 0.f};
            }
            (void)p0; (void)p1;

            bf16x8 b0 = *reinterpret_cast<const bf16x8*>(
                &L[r0 * 512 + ((cb) ^ ((r0 & 7) << 4))]);
            bf16x8 b1 = *reinterpret_cast<const bf16x8*>(
                &L[r1 * 512 + ((cb) ^ ((r1 & 7) << 4))]);

            #pragma unroll
            for (int ks = 0; ks < 8; ++ks) {
                bf16x8 nb0 = b0, nb1 = b1;
                if (ks < 7) {
                    const int bcol = (ks + 1) * 64 + cb;
                    nb0 = *reinterpret_cast<const bf16x8*>(
                        &L[r0 * 512 + (bcol ^ ((r0 & 7) << 4))]);
                    nb1 = *reinterpret_cast<const bf16x8*>(
                        &L[r1 * 512 + (bcol ^ ((r1 & 7) << 4))]);
                }
                __builtin_amdgcn_s_setprio(1);
                #pragma unroll
                for (int f = 0; f < 4; ++f)
                    acc[f][0] = __builtin_amdgcn_mfma_f32_16x16x32_bf16(
                        afrag[f][ks], b0, acc[f][0], 0, 0, 0);
                #pragma unroll
                for (int f = 0; f < 4; ++f)
                    acc[f][1] = __builtin_amdgcn_mfma_f32_16x16x32_bf16(
                        afrag[f][ks], b1, acc[f][1], 0, 0, 0);
                __builtin_amdgcn_s_setprio(0);
                b0 = nb0;
                b1 = nb1;
            }

            // acc[f][g][r] = (2log2e)*s[row=f*16+(lane>>4)*4+r][col group]
            #pragma unroll
            for (int f = 0; f < 4; ++f)
                #pragma unroll
                for (int g = 0; g < 2; ++g)
                    #pragma unroll
                    for (int r = 0; r < 4; ++r)
                        rowsum[f][r] += __builtin_amdgcn_exp2f(acc[f][g][r]);
        }
    }

    // sum across the 16 lanes sharing (lane>>4)
    #pragma unroll
    for (int f = 0; f < 4; ++f)
        #pragma unroll
        for (int r = 0; r < 4; ++r) {
            float s = rowsum[f][r];
            s += __shfl_xor(s, 1);
            s += __shfl_xor(s, 2);
            s += __shfl_xor(s, 4);
            s += __shfl_xor(s, 8);
            rowsum[f][r] = s;
        }

    if ((lane & 15) == 0) {
        const int rbase = mbase + w * 64 + (lane >> 4) * 4;
        #pragma unroll
        for (int f = 0; f < 4; ++f)
            #pragma unroll
            for (int r = 0; r < 4; ++r)
                partial[(size_t)blockIdx.y * MROWS + rbase + f * 16 + r] = rowsum[f][r];
    }
}

__global__ void finalize_kernel(const float* __restrict__ partial,
                                float* __restrict__ out) {
    const int i = blockIdx.x * blockDim.x + threadIdx.x;
    float s = 0.f;
    #pragma unroll
    for (int p = 0; p < NSPLIT; ++p) s += partial[(size_t)p * MROWS + i];
    // sum holds Sum_j e^{2 s_ij}; energy = -(log(sum)-log M)/2 + 0.5 + 0.5
    out[i] = -0.5f * (logf(s) - logf((float)NROWS)) + 1.0f;
}

extern "C" void kernel_launch(void* const* d_in, const int* in_sizes, int n_in,
                              void* d_out, int out_size, void* d_ws, size_t ws_size,
                              hipStream_t stream) {
    const float* x = (const float*)d_in[0];
    const float* a = (const float*)d_in[1];
    float* out = (float*)d_out;

    char* ws = (char*)d_ws;
    size_t off = 0;
    __hip_bfloat16* xb = (__hip_bfloat16*)(ws + off); off += (size_t)MROWS * KDIM * 2;  // 4 MiB
    __hip_bfloat16* ab = (__hip_bfloat16*)(ws + off); off += (size_t)NROWS * KDIM * 2;  // 4 MiB
    float* partial     = (float*)(ws + off);          // NSPLIT*MROWS*4 = 512 KiB

    normalize_kernel<<<(2 * MROWS) / 4, 256, 0, stream>>>(x, a, xb, ab);
    expsum_kernel<<<dim3(MROWS / BM, NSPLIT), 256, 0, stream>>>(xb, ab, partial);
    finalize_kernel<<<MROWS / 256, 256, 0, stream>>>(partial, out);
}